// Round 2
// baseline (218.186 us; speedup 1.0000x reference)
//
#include <hip/hip_runtime.h>

// NEAT windowed-DAG forward:
//   values[0:16] = x; for i in 0..511: v = tanh(dot(values[i:i+16], w[i]) + b[i]) * r[i]
//   out = values[T-64:T]  (nodes 448..511)
//
// R1 fix: round 0's win[16] array was demoted to scratch (VGPR_Count=12,
// VALUBusy 5%, 162us). Now the 16-slot circular window is 16 NAMED floats,
// rotated via macro argument order -> cannot spill to scratch as an array.
// Dot product uses 4 partial chains so the node->node critical path is
// ~1 FMA + 2 adds + tanh instead of 16 serial FMAs.

constexpr int kFanin  = 16;
constexpr int kNodes  = 512;
constexpr int kNOut   = 64;
constexpr int kBatch  = 32768;
constexpr int kOutStartGroup = (kNodes - kNOut) / 16;  // group 28 (node 448)

// tanh(x) = 1 - 2/(exp2(2*log2e*x)+1). exp2/rcp are HW transcendentals
// (~1ulp): e=+inf -> 1, e=0 -> -1, NaN-free. Verified absmax 3.9e-3 in R0.
#define NODE(K, A0,A1,A2,A3,A4,A5,A6,A7,A8,A9,A10,A11,A12,A13,A14,A15)      \
  {                                                                          \
    const float* __restrict__ wr = wg + (K) * kFanin;                        \
    float p0 = fmaf(A0,  wr[0],  bg[K]);                                     \
    float p1 = A4  * wr[4];                                                  \
    float p2 = A8  * wr[8];                                                  \
    float p3 = A12 * wr[12];                                                 \
    p0 = fmaf(A1,  wr[1],  p0);  p1 = fmaf(A5,  wr[5],  p1);                 \
    p2 = fmaf(A9,  wr[9],  p2);  p3 = fmaf(A13, wr[13], p3);                 \
    p0 = fmaf(A2,  wr[2],  p0);  p1 = fmaf(A6,  wr[6],  p1);                 \
    p2 = fmaf(A10, wr[10], p2);  p3 = fmaf(A14, wr[14], p3);                 \
    p0 = fmaf(A3,  wr[3],  p0);  p1 = fmaf(A7,  wr[7],  p1);                 \
    p2 = fmaf(A11, wr[11], p2);  p3 = fmaf(A15, wr[15], p3);                 \
    float acc = (p0 + p1) + (p2 + p3);                                       \
    float e = __builtin_amdgcn_exp2f(acc * 2.8853900817779268f);             \
    float t = fmaf(-2.0f, __builtin_amdgcn_rcpf(e + 1.0f), 1.0f);            \
    A0 = t * rg[K];                                                          \
    if (g >= kOutStartGroup) op[(g - kOutStartGroup) * 16 + (K)] = A0;       \
  }

__global__ __launch_bounds__(128) void neat_fwd(
    const float* __restrict__ x,      // [B, 16]
    const float* __restrict__ w,      // [512, 16]
    const float* __restrict__ bias,   // [512]
    const float* __restrict__ resp,   // [512]
    float* __restrict__ out)          // [B, 64]
{
    const int b = blockIdx.x * blockDim.x + threadIdx.x;

    const float4* __restrict__ x4 = reinterpret_cast<const float4*>(x) + (size_t)b * 4;
    float4 a0 = x4[0], a1 = x4[1], a2 = x4[2], a3 = x4[3];
    // Window slot s holds value of global node g with g == s (mod 16).
    float v0  = a0.x, v1  = a0.y, v2  = a0.z, v3  = a0.w;
    float v4  = a1.x, v5  = a1.y, v6  = a1.z, v7  = a1.w;
    float v8  = a2.x, v9  = a2.y, v10 = a2.z, v11 = a2.w;
    float v12 = a3.x, v13 = a3.y, v14 = a3.z, v15 = a3.w;

    float* __restrict__ op = out + (size_t)b * kNOut;

    for (int g = 0; g < kNodes / 16; ++g) {
        const float* __restrict__ wg = w    + g * (16 * kFanin);
        const float* __restrict__ bg = bias + g * 16;
        const float* __restrict__ rg = resp + g * 16;
        // Node i = g*16+k reads slots (k+j)&15, j=0..15 (j=15 = newest value),
        // writes slot k (its own first argument).
        NODE( 0, v0 ,v1 ,v2 ,v3 ,v4 ,v5 ,v6 ,v7 ,v8 ,v9 ,v10,v11,v12,v13,v14,v15)
        NODE( 1, v1 ,v2 ,v3 ,v4 ,v5 ,v6 ,v7 ,v8 ,v9 ,v10,v11,v12,v13,v14,v15,v0 )
        NODE( 2, v2 ,v3 ,v4 ,v5 ,v6 ,v7 ,v8 ,v9 ,v10,v11,v12,v13,v14,v15,v0 ,v1 )
        NODE( 3, v3 ,v4 ,v5 ,v6 ,v7 ,v8 ,v9 ,v10,v11,v12,v13,v14,v15,v0 ,v1 ,v2 )
        NODE( 4, v4 ,v5 ,v6 ,v7 ,v8 ,v9 ,v10,v11,v12,v13,v14,v15,v0 ,v1 ,v2 ,v3 )
        NODE( 5, v5 ,v6 ,v7 ,v8 ,v9 ,v10,v11,v12,v13,v14,v15,v0 ,v1 ,v2 ,v3 ,v4 )
        NODE( 6, v6 ,v7 ,v8 ,v9 ,v10,v11,v12,v13,v14,v15,v0 ,v1 ,v2 ,v3 ,v4 ,v5 )
        NODE( 7, v7 ,v8 ,v9 ,v10,v11,v12,v13,v14,v15,v0 ,v1 ,v2 ,v3 ,v4 ,v5 ,v6 )
        NODE( 8, v8 ,v9 ,v10,v11,v12,v13,v14,v15,v0 ,v1 ,v2 ,v3 ,v4 ,v5 ,v6 ,v7 )
        NODE( 9, v9 ,v10,v11,v12,v13,v14,v15,v0 ,v1 ,v2 ,v3 ,v4 ,v5 ,v6 ,v7 ,v8 )
        NODE(10, v10,v11,v12,v13,v14,v15,v0 ,v1 ,v2 ,v3 ,v4 ,v5 ,v6 ,v7 ,v8 ,v9 )
        NODE(11, v11,v12,v13,v14,v15,v0 ,v1 ,v2 ,v3 ,v4 ,v5 ,v6 ,v7 ,v8 ,v9 ,v10)
        NODE(12, v12,v13,v14,v15,v0 ,v1 ,v2 ,v3 ,v4 ,v5 ,v6 ,v7 ,v8 ,v9 ,v10,v11)
        NODE(13, v13,v14,v15,v0 ,v1 ,v2 ,v3 ,v4 ,v5 ,v6 ,v7 ,v8 ,v9 ,v10,v11,v12)
        NODE(14, v14,v15,v0 ,v1 ,v2 ,v3 ,v4 ,v5 ,v6 ,v7 ,v8 ,v9 ,v10,v11,v12,v13)
        NODE(15, v15,v0 ,v1 ,v2 ,v3 ,v4 ,v5 ,v6 ,v7 ,v8 ,v9 ,v10,v11,v12,v13,v14)
    }
}

extern "C" void kernel_launch(void* const* d_in, const int* in_sizes, int n_in,
                              void* d_out, int out_size, void* d_ws, size_t ws_size,
                              hipStream_t stream) {
    const float* x    = (const float*)d_in[0];
    const float* w    = (const float*)d_in[1];
    const float* bias = (const float*)d_in[2];
    const float* resp = (const float*)d_in[3];
    float* out = (float*)d_out;
    // in_sizes[4] (src_idx) encodes the fixed windowed topology; hardcoded above.
    dim3 block(128);
    dim3 grid(kBatch / 128);   // 256 blocks -> 1 per CU, 2 waves/CU (2 of 4 SIMDs)
    hipLaunchKernelGGL(neat_fwd, grid, block, 0, stream, x, w, bias, resp, out);
}

// Round 3
// 116.104 us; speedup vs baseline: 1.8792x; 1.8792x over previous
//
#include <hip/hip_runtime.h>

// NEAT windowed-DAG forward:
//   values[0:16] = x; for i in 0..511: v = tanh(dot(values[i:i+16], w[i]) + b[i]) * r[i]
//   out = values[T-64:T]  (nodes 448..511)
//
// R2: R0 and R1 benched IDENTICAL (all counters) -> window regs were never the
// issue; bottleneck is per-node global weight loads with 0.5 waves/SIMD = full
// latency exposure (~770 cyc/node, VALUBusy 6%). Fix:
//  (a) stage all params in LDS once per block (40 KB) -> fine-grained lgkmcnt
//      pipelining of next-node loads under current-node compute;
//  (b) fold tanh's 2*log2(e) scale into staged w,b; pre-sum 15 products + bias
//      off-chain so the node->node serial chain is exactly:
//      fma(v_prev) -> exp2 -> add -> rcp -> fma(-2r,.,r)  (~50 cyc).
// Latency floor: 512 * ~50 cyc ~= 11 us.

constexpr int kFanin  = 16;
constexpr int kNodes  = 512;
constexpr int kNOut   = 64;
constexpr int kBatch  = 32768;
constexpr int kOutStartGroup = (kNodes - kNOut) / 16;  // group 28 (node 448)
constexpr int kStride = 20;   // floats per node in LDS: 16 wK, bK, r, m2r, pad
constexpr float kScale = 2.8853900817779268f;  // 2*log2(e)

// Node i = g*16+K reads window slots (K+j)&15 (A15 = just-computed previous
// node -> keep it in the FINAL fma so everything else is off the serial chain).
#define NODE(K, A0,A1,A2,A3,A4,A5,A6,A7,A8,A9,A10,A11,A12,A13,A14,A15)       \
  {                                                                          \
    const float* __restrict__ nb = lds + (g * 16 + (K)) * kStride;           \
    float4 q0 = *reinterpret_cast<const float4*>(nb + 0);                    \
    float4 q1 = *reinterpret_cast<const float4*>(nb + 4);                    \
    float4 q2 = *reinterpret_cast<const float4*>(nb + 8);                    \
    float4 q3 = *reinterpret_cast<const float4*>(nb + 12);                   \
    float bK = nb[16], rr = nb[17], m2r = nb[18];                            \
    float p0 = fmaf(A0, q0.x, bK);                                           \
    float p1 = A4 * q1.x;                                                    \
    float p2 = A8 * q2.x;                                                    \
    float p3 = A12 * q3.x;                                                   \
    p0 = fmaf(A1,  q0.y, p0);  p1 = fmaf(A5,  q1.y, p1);                     \
    p2 = fmaf(A9,  q2.y, p2);  p3 = fmaf(A13, q3.y, p3);                     \
    p0 = fmaf(A2,  q0.z, p0);  p1 = fmaf(A6,  q1.z, p1);                     \
    p2 = fmaf(A10, q2.z, p2);  p3 = fmaf(A14, q3.z, p3);                     \
    p0 = fmaf(A3,  q0.w, p0);  p1 = fmaf(A7,  q1.w, p1);                     \
    p2 = fmaf(A11, q2.w, p2);                                                \
    float pre = (p0 + p1) + (p2 + p3);                                       \
    float acc = fmaf(A15, q3.w, pre);        /* serial chain starts here */  \
    float e = __builtin_amdgcn_exp2f(acc);                                   \
    float t = fmaf(m2r, __builtin_amdgcn_rcpf(e + 1.0f), rr);                \
    A0 = t;                                                                  \
    if (g >= kOutStartGroup) op[(g - kOutStartGroup) * 16 + (K)] = t;        \
  }

__global__ __launch_bounds__(128) void neat_fwd(
    const float* __restrict__ x,      // [B, 16]
    const float* __restrict__ w,      // [512, 16]
    const float* __restrict__ bias,   // [512]
    const float* __restrict__ resp,   // [512]
    float* __restrict__ out)          // [B, 64]
{
    __shared__ float lds[kNodes * kStride];   // 40960 B

    const int t = threadIdx.x;

    // ---- Stage params into LDS (scaled) ----
    const float4* __restrict__ w4 = reinterpret_cast<const float4*>(w);
    #pragma unroll
    for (int j = 0; j < 16; ++j) {
        int i4 = t + j * 128;                 // [0, 2048)
        float4 v = w4[i4];
        int node = i4 >> 2, pos = (i4 & 3) << 2;
        float4 s = make_float4(v.x * kScale, v.y * kScale, v.z * kScale, v.w * kScale);
        *reinterpret_cast<float4*>(lds + node * kStride + pos) = s;
    }
    #pragma unroll
    for (int j = 0; j < 4; ++j) {
        int n = t + j * 128;
        float b = bias[n], r = resp[n];
        lds[n * kStride + 16] = b * kScale;
        lds[n * kStride + 17] = r;
        lds[n * kStride + 18] = -2.0f * r;
    }

    const int b = blockIdx.x * blockDim.x + t;
    const float4* __restrict__ x4 = reinterpret_cast<const float4*>(x) + (size_t)b * 4;
    float4 a0 = x4[0], a1 = x4[1], a2 = x4[2], a3 = x4[3];
    float v0  = a0.x, v1  = a0.y, v2  = a0.z, v3  = a0.w;
    float v4  = a1.x, v5  = a1.y, v6  = a1.z, v7  = a1.w;
    float v8  = a2.x, v9  = a2.y, v10 = a2.z, v11 = a2.w;
    float v12 = a3.x, v13 = a3.y, v14 = a3.z, v15 = a3.w;

    float* __restrict__ op = out + (size_t)b * kNOut;

    __syncthreads();

    for (int g = 0; g < kNodes / 16; ++g) {
        NODE( 0, v0 ,v1 ,v2 ,v3 ,v4 ,v5 ,v6 ,v7 ,v8 ,v9 ,v10,v11,v12,v13,v14,v15)
        NODE( 1, v1 ,v2 ,v3 ,v4 ,v5 ,v6 ,v7 ,v8 ,v9 ,v10,v11,v12,v13,v14,v15,v0 )
        NODE( 2, v2 ,v3 ,v4 ,v5 ,v6 ,v7 ,v8 ,v9 ,v10,v11,v12,v13,v14,v15,v0 ,v1 )
        NODE( 3, v3 ,v4 ,v5 ,v6 ,v7 ,v8 ,v9 ,v10,v11,v12,v13,v14,v15,v0 ,v1 ,v2 )
        NODE( 4, v4 ,v5 ,v6 ,v7 ,v8 ,v9 ,v10,v11,v12,v13,v14,v15,v0 ,v1 ,v2 ,v3 )
        NODE( 5, v5 ,v6 ,v7 ,v8 ,v9 ,v10,v11,v12,v13,v14,v15,v0 ,v1 ,v2 ,v3 ,v4 )
        NODE( 6, v6 ,v7 ,v8 ,v9 ,v10,v11,v12,v13,v14,v15,v0 ,v1 ,v2 ,v3 ,v4 ,v5 )
        NODE( 7, v7 ,v8 ,v9 ,v10,v11,v12,v13,v14,v15,v0 ,v1 ,v2 ,v3 ,v4 ,v5 ,v6 )
        NODE( 8, v8 ,v9 ,v10,v11,v12,v13,v14,v15,v0 ,v1 ,v2 ,v3 ,v4 ,v5 ,v6 ,v7 )
        NODE( 9, v9 ,v10,v11,v12,v13,v14,v15,v0 ,v1 ,v2 ,v3 ,v4 ,v5 ,v6 ,v7 ,v8 )
        NODE(10, v10,v11,v12,v13,v14,v15,v0 ,v1 ,v2 ,v3 ,v4 ,v5 ,v6 ,v7 ,v8 ,v9 )
        NODE(11, v11,v12,v13,v14,v15,v0 ,v1 ,v2 ,v3 ,v4 ,v5 ,v6 ,v7 ,v8 ,v9 ,v10)
        NODE(12, v12,v13,v14,v15,v0 ,v1 ,v2 ,v3 ,v4 ,v5 ,v6 ,v7 ,v8 ,v9 ,v10,v11)
        NODE(13, v13,v14,v15,v0 ,v1 ,v2 ,v3 ,v4 ,v5 ,v6 ,v7 ,v8 ,v9 ,v10,v11,v12)
        NODE(14, v14,v15,v0 ,v1 ,v2 ,v3 ,v4 ,v5 ,v6 ,v7 ,v8 ,v9 ,v10,v11,v12,v13)
        NODE(15, v15,v0 ,v1 ,v2 ,v3 ,v4 ,v5 ,v6 ,v7 ,v8 ,v9 ,v10,v11,v12,v13,v14)
    }
}

extern "C" void kernel_launch(void* const* d_in, const int* in_sizes, int n_in,
                              void* d_out, int out_size, void* d_ws, size_t ws_size,
                              hipStream_t stream) {
    const float* x    = (const float*)d_in[0];
    const float* w    = (const float*)d_in[1];
    const float* bias = (const float*)d_in[2];
    const float* resp = (const float*)d_in[3];
    float* out = (float*)d_out;
    // in_sizes[4] (src_idx) encodes the fixed windowed topology; hardcoded above.
    dim3 block(128);
    dim3 grid(kBatch / 128);   // 256 blocks -> 1 per CU, 2 waves/CU
    hipLaunchKernelGGL(neat_fwd, grid, block, 0, stream, x, w, bias, resp, out);
}

// Round 4
// 114.143 us; speedup vs baseline: 1.9115x; 1.0172x over previous
//
#include <hip/hip_runtime.h>

// NEAT windowed-DAG forward:
//   values[0:16] = x; for i in 0..511: v = tanh(dot(values[i:i+16], w[i]) + b[i]) * r[i]
//   out = values[T-64:T]  (nodes 448..511)
//
// R4: R3 (LDS params, no prefetch) = 301 cyc/node: compiler issued each node's
// 5 ds_reads just before use -> ~120cyc LDS latency exposed per node + addr VALU.
// Fix: explicit register prefetch pipeline, depth 3, via 4 rotating float4
// buffer sets (SROA-safe: R0==R1 proved compile-time-indexed arrays stay in
// regs). Buffer = K&3 (16 % 4 == 0 -> phase-invariant across g-loop).
// Target ~60-70 cyc/node ~= 15-24 us.

constexpr int kFanin  = 16;
constexpr int kNodes  = 512;
constexpr int kNOut   = 64;
constexpr int kBatch  = 32768;
constexpr int kOutStartGroup = (kNodes - kNOut) / 16;  // group 28 (node 448)
constexpr int kStride = 20;                 // floats per node in LDS
constexpr int kLdsNodes = kNodes + 3;       // +3 prefetch-overrun slots (never consumed)
constexpr float kScale = 2.8853900817779268f;  // 2*log2(e)

// Load node IDX's params into buffer slot PF (compile-time PF after unroll).
#define PREFETCH(PF, IDX)                                                     \
  {                                                                           \
    const float* __restrict__ nb = lds + (IDX) * kStride;                     \
    pw0[PF] = *reinterpret_cast<const float4*>(nb + 0);                       \
    pw1[PF] = *reinterpret_cast<const float4*>(nb + 4);                       \
    pw2[PF] = *reinterpret_cast<const float4*>(nb + 8);                       \
    pw3[PF] = *reinterpret_cast<const float4*>(nb + 12);                      \
    pm [PF] = *reinterpret_cast<const float4*>(nb + 16);                      \
  }

// Node i = g*16+K. A0 = oldest window slot (weight j=0, overwritten with the
// new value), A15 = newest (previous node, weight j=15 -> kept in the FINAL
// fma so only it sits on the serial chain).
// qm = (b*scale, r, -2r, pad). Chain: fma -> exp2 -> add -> rcp -> fma.
#define NODE(K, A0,A1,A2,A3,A4,A5,A6,A7,A8,A9,A10,A11,A12,A13,A14,A15)       \
  {                                                                          \
    PREFETCH(((K)+3)&3, g*16 + (K) + 3);                                     \
    const int pb = (K)&3;                                                    \
    float4 qa = pw0[pb], qb = pw1[pb], qc = pw2[pb], qd = pw3[pb];           \
    float4 qm = pm[pb];                                                      \
    float p0 = fmaf(A0, qa.x, qm.x);                                         \
    float p1 = A4  * qb.x;                                                   \
    float p2 = A8  * qc.x;                                                   \
    float p3 = A12 * qd.x;                                                   \
    p0 = fmaf(A1,  qa.y, p0);  p1 = fmaf(A5,  qb.y, p1);                     \
    p2 = fmaf(A9,  qc.y, p2);  p3 = fmaf(A13, qd.y, p3);                     \
    p0 = fmaf(A2,  qa.z, p0);  p1 = fmaf(A6,  qb.z, p1);                     \
    p2 = fmaf(A10, qc.z, p2);  p3 = fmaf(A14, qd.z, p3);                     \
    p0 = fmaf(A3,  qa.w, p0);  p1 = fmaf(A7,  qb.w, p1);                     \
    p2 = fmaf(A11, qc.w, p2);                                                \
    float pre = (p0 + p1) + (p2 + p3);                                       \
    float acc = fmaf(A15, qd.w, pre);      /* serial chain starts here */    \
    float e = __builtin_amdgcn_exp2f(acc);                                   \
    float t = fmaf(qm.z, __builtin_amdgcn_rcpf(e + 1.0f), qm.y);             \
    A0 = t;                                                                  \
    if (g >= kOutStartGroup) op[(g - kOutStartGroup) * 16 + (K)] = t;        \
  }

__global__ __launch_bounds__(128) void neat_fwd(
    const float* __restrict__ x,      // [B, 16]
    const float* __restrict__ w,      // [512, 16]
    const float* __restrict__ bias,   // [512]
    const float* __restrict__ resp,   // [512]
    float* __restrict__ out)          // [B, 64]
{
    __shared__ float lds[kLdsNodes * kStride];   // 41200 B

    const int t = threadIdx.x;

    // ---- Stage params into LDS, pre-scaled by 2*log2(e) ----
    const float4* __restrict__ w4 = reinterpret_cast<const float4*>(w);
    #pragma unroll
    for (int j = 0; j < 16; ++j) {
        int i4 = t + j * 128;                 // [0, 2048)
        float4 v = w4[i4];
        int node = i4 >> 2, pos = (i4 & 3) << 2;
        float4 s = make_float4(v.x * kScale, v.y * kScale, v.z * kScale, v.w * kScale);
        *reinterpret_cast<float4*>(lds + node * kStride + pos) = s;
    }
    #pragma unroll
    for (int j = 0; j < 4; ++j) {
        int n = t + j * 128;
        float b = bias[n], r = resp[n];
        lds[n * kStride + 16] = b * kScale;
        lds[n * kStride + 17] = r;
        lds[n * kStride + 18] = -2.0f * r;
    }

    const int b = blockIdx.x * blockDim.x + t;
    const float4* __restrict__ x4 = reinterpret_cast<const float4*>(x) + (size_t)b * 4;
    float4 a0 = x4[0], a1 = x4[1], a2 = x4[2], a3 = x4[3];
    float v0  = a0.x, v1  = a0.y, v2  = a0.z, v3  = a0.w;
    float v4  = a1.x, v5  = a1.y, v6  = a1.z, v7  = a1.w;
    float v8  = a2.x, v9  = a2.y, v10 = a2.z, v11 = a2.w;
    float v12 = a3.x, v13 = a3.y, v14 = a3.z, v15 = a3.w;

    float* __restrict__ op = out + (size_t)b * kNOut;

    __syncthreads();

    // Param prefetch pipeline: node i lives in buffer i&3, loaded 3 nodes early.
    float4 pw0[4], pw1[4], pw2[4], pw3[4], pm[4];
    PREFETCH(0, 0)
    PREFETCH(1, 1)
    PREFETCH(2, 2)

    #pragma unroll 1
    for (int g = 0; g < kNodes / 16; ++g) {
        NODE( 0, v0 ,v1 ,v2 ,v3 ,v4 ,v5 ,v6 ,v7 ,v8 ,v9 ,v10,v11,v12,v13,v14,v15)
        NODE( 1, v1 ,v2 ,v3 ,v4 ,v5 ,v6 ,v7 ,v8 ,v9 ,v10,v11,v12,v13,v14,v15,v0 )
        NODE( 2, v2 ,v3 ,v4 ,v5 ,v6 ,v7 ,v8 ,v9 ,v10,v11,v12,v13,v14,v15,v0 ,v1 )
        NODE( 3, v3 ,v4 ,v5 ,v6 ,v7 ,v8 ,v9 ,v10,v11,v12,v13,v14,v15,v0 ,v1 ,v2 )
        NODE( 4, v4 ,v5 ,v6 ,v7 ,v8 ,v9 ,v10,v11,v12,v13,v14,v15,v0 ,v1 ,v2 ,v3 )
        NODE( 5, v5 ,v6 ,v7 ,v8 ,v9 ,v10,v11,v12,v13,v14,v15,v0 ,v1 ,v2 ,v3 ,v4 )
        NODE( 6, v6 ,v7 ,v8 ,v9 ,v10,v11,v12,v13,v14,v15,v0 ,v1 ,v2 ,v3 ,v4 ,v5 )
        NODE( 7, v7 ,v8 ,v9 ,v10,v11,v12,v13,v14,v15,v0 ,v1 ,v2 ,v3 ,v4 ,v5 ,v6 )
        NODE( 8, v8 ,v9 ,v10,v11,v12,v13,v14,v15,v0 ,v1 ,v2 ,v3 ,v4 ,v5 ,v6 ,v7 )
        NODE( 9, v9 ,v10,v11,v12,v13,v14,v15,v0 ,v1 ,v2 ,v3 ,v4 ,v5 ,v6 ,v7 ,v8 )
        NODE(10, v10,v11,v12,v13,v14,v15,v0 ,v1 ,v2 ,v3 ,v4 ,v5 ,v6 ,v7 ,v8 ,v9 )
        NODE(11, v11,v12,v13,v14,v15,v0 ,v1 ,v2 ,v3 ,v4 ,v5 ,v6 ,v7 ,v8 ,v9 ,v10)
        NODE(12, v12,v13,v14,v15,v0 ,v1 ,v2 ,v3 ,v4 ,v5 ,v6 ,v7 ,v8 ,v9 ,v10,v11)
        NODE(13, v13,v14,v15,v0 ,v1 ,v2 ,v3 ,v4 ,v5 ,v6 ,v7 ,v8 ,v9 ,v10,v11,v12)
        NODE(14, v14,v15,v0 ,v1 ,v2 ,v3 ,v4 ,v5 ,v6 ,v7 ,v8 ,v9 ,v10,v11,v12,v13)
        NODE(15, v15,v0 ,v1 ,v2 ,v3 ,v4 ,v5 ,v6 ,v7 ,v8 ,v9 ,v10,v11,v12,v13,v14)
    }
}

extern "C" void kernel_launch(void* const* d_in, const int* in_sizes, int n_in,
                              void* d_out, int out_size, void* d_ws, size_t ws_size,
                              hipStream_t stream) {
    const float* x    = (const float*)d_in[0];
    const float* w    = (const float*)d_in[1];
    const float* bias = (const float*)d_in[2];
    const float* resp = (const float*)d_in[3];
    float* out = (float*)d_out;
    // in_sizes[4] (src_idx) encodes the fixed windowed topology; hardcoded above.
    dim3 block(128);
    dim3 grid(kBatch / 128);   // 256 blocks -> 1 per CU, 2 waves/CU
    hipLaunchKernelGGL(neat_fwd, grid, block, 0, stream, x, w, bias, resp, out);
}